// Round 3
// baseline (578.138 us; speedup 1.0000x reference)
//
#include <hip/hip_runtime.h>
#include <hip/hip_bf16.h>

#define SLEN  256
#define BSZ   8
#define NHEAD 16
#define DHEAD 64
#define INDIM 1024
#define LN_EPS 1e-5f

typedef __attribute__((ext_vector_type(4))) float f32x4;
typedef __attribute__((ext_vector_type(8))) short bf16x8;

__device__ __forceinline__ int f_as_i(float f) { union { float f; int i; } u; u.f = f; return u.i; }
__device__ __forceinline__ float i_as_f(int i) { union { float f; int i; } u; u.i = i; return u.f; }

__device__ inline unsigned short f2bf(float x) {
  __hip_bfloat16 b = __float2bfloat16(x);
  union { __hip_bfloat16 b; unsigned short u; } cv;
  cv.b = b;
  return cv.u;
}

// DPP move, invalid lanes -> 0 (for sum)
template <int CTRL>
__device__ __forceinline__ float dpp0(float x) {
  return i_as_f(__builtin_amdgcn_update_dpp(0, f_as_i(x), CTRL, 0xF, 0xF, true));
}
// DPP move, invalid lanes -> self (for max)
template <int CTRL>
__device__ __forceinline__ float dppS(float x) {
  int xi = f_as_i(x);
  return i_as_f(__builtin_amdgcn_update_dpp(xi, xi, CTRL, 0xF, 0xF, false));
}

__device__ __forceinline__ float wave_sum64(float v) {
  v += dpp0<0x111>(v);
  v += dpp0<0x112>(v);
  v += dpp0<0x114>(v);
  v += dpp0<0x118>(v);
  v += dpp0<0x142>(v);  // row_bcast:15
  v += dpp0<0x143>(v);  // row_bcast:31
  return i_as_f(__builtin_amdgcn_readlane(f_as_i(v), 63));
}

__device__ __forceinline__ float wave_max64(float v) {
  v = fmaxf(v, dppS<0x111>(v));
  v = fmaxf(v, dppS<0x112>(v));
  v = fmaxf(v, dppS<0x114>(v));
  v = fmaxf(v, dppS<0x118>(v));
  v = fmaxf(v, dppS<0x142>(v));
  v = fmaxf(v, dppS<0x143>(v));
  return i_as_f(__builtin_amdgcn_readlane(f_as_i(v), 63));
}

// --------------------------------------------------------------------------
// Fused kernel: blocks 0..127 = SRWM scan (one chain each);
// blocks 128..1151 = out_w fp32->bf16; blocks 1152..3199 = LN row stats.
// --------------------------------------------------------------------------
__global__ __launch_bounds__(256, 1) void scan_prep_k(
    const float* __restrict__ h,
    const float* __restrict__ Wy0,
    const float* __restrict__ Wq0,
    const float* __restrict__ Wk0,
    const float* __restrict__ wb0,
    const float* __restrict__ outw,
    unsigned short* __restrict__ outw_bf,
    float* __restrict__ stats,
    unsigned short* __restrict__ ys_bf) {
  const int bid = blockIdx.x;
  const int tid = threadIdx.x;

  if (bid >= 128) {
    const int pb = bid - 128;
    if (pb < 1024) {
      int i = (pb * 256 + tid) * 4;
      float4 v = *(const float4*)(outw + i);
      ushort4 o;
      o.x = f2bf(v.x); o.y = f2bf(v.y); o.z = f2bf(v.z); o.w = f2bf(v.w);
      *(ushort4*)(outw_bf + i) = o;
    } else {
      int r = pb - 1024;
      const float* row = h + (size_t)r * INDIM;
      float4 v = *(const float4*)(row + tid * 4);
      float s  = v.x + v.y + v.z + v.w;
      float s2 = v.x * v.x + v.y * v.y + v.z * v.z + v.w * v.w;
      s  = wave_sum64(s);
      s2 = wave_sum64(s2);
      __shared__ float ls[4], ls2[4];
      int wv = tid >> 6;
      if ((tid & 63) == 0) { ls[wv] = s; ls2[wv] = s2; }
      __syncthreads();
      if (tid == 0) {
        float S  = ls[0] + ls[1] + ls[2] + ls[3];
        float S2 = ls2[0] + ls2[1] + ls2[2] + ls2[3];
        float mu = S * (1.0f / INDIM);
        float var = S2 * (1.0f / INDIM) - mu * mu;
        stats[2 * r]     = mu;
        stats[2 * r + 1] = rsqrtf(var + LN_EPS);
      }
    }
    return;
  }

  // ---------------- SRWM scan: one chain per block ----------------
  const int chain = bid;
  const int b    = chain >> 4;
  const int head = chain & 15;
  const int wv   = __builtin_amdgcn_readfirstlane(tid >> 6);
  const int lane = tid & 63;

  __shared__ __align__(16) float eqk[2][2][64];  // [buf][0]=exp(vq-m), [1]=exp(vk-m)
  __shared__ float sbuf[2][2];                   // [buf][{q,k}] = sum of exps
  __shared__ float betabuf[2][4];

  const float* xrow0 = h + (size_t)b * INDIM + head * DHEAD;  // wave-uniform base

  if (wv < 3) {
    const float* Wsel = (wv == 0) ? Wy0 : ((wv == 1) ? Wq0 : Wk0);
    const float* wrow = Wsel + (size_t)head * DHEAD * DHEAD + (size_t)lane * DHEAD;
    float w[64];
    #pragma unroll
    for (int j = 0; j < 64; j += 4) {
      float4 t4 = *(const float4*)(wrow + j);
      w[j] = t4.x; w[j + 1] = t4.y; w[j + 2] = t4.z; w[j + 3] = t4.w;
    }
    // x_0 via wave-uniform (scalar) loads
    float xs[64];
    #pragma unroll
    for (int j = 0; j < 64; ++j) xs[j] = xrow0[j];

    for (int t = 0; t < SLEN; ++t) {
      const int buf = t & 1;
      // ---- matvec: v = W x_t (x broadcast free via SGPRs) ----
      float a0 = 0.f, a1 = 0.f, a2 = 0.f, a3 = 0.f;
      #pragma unroll
      for (int j = 0; j < 64; j += 4) {
        a0 += w[j]     * xs[j];
        a1 += w[j + 1] * xs[j + 1];
        a2 += w[j + 2] * xs[j + 2];
        a3 += w[j + 3] * xs[j + 3];
      }
      float v = (a0 + a1) + (a2 + a3);

      // prefetch x_{t+1} (scalar loads; consumed next step)
      if (t + 1 < SLEN) {
        const float* xn = xrow0 + (size_t)(t + 1) * BSZ * INDIM;
        #pragma unroll
        for (int j = 0; j < 64; ++j) xs[j] = xn[j];
      }

      if (wv == 0) {
        ys_bf[(size_t)(t * BSZ + b) * INDIM + head * DHEAD + lane] = f2bf(v);
      } else {
        // publish unnormalized exp early; sum after (off critical path)
        float m = wave_max64(v);
        float e = __expf(v - m);
        eqk[buf][wv - 1][lane] = e;
        float ss = wave_sum64(e);
        if (lane == 0) sbuf[buf][wv - 1] = ss;
      }
      __syncthreads();

      // ---- region C: dv = rq*(W eq) - rk*(W ek); W += (beta*dv*rk) * ek ----
      float rq = __fdividef(1.f, sbuf[buf][0]);
      float rk = __fdividef(1.f, sbuf[buf][1]);
      float beta_c = betabuf[buf][wv];
      float ekr[64];
      float dA0 = 0.f, dA1 = 0.f, dA2 = 0.f, dA3 = 0.f;
      float dB0 = 0.f, dB1 = 0.f, dB2 = 0.f, dB3 = 0.f;
      #pragma unroll
      for (int j = 0; j < 64; j += 4) {
        float4 q4 = *(const float4*)(&eqk[buf][0][j]);
        float4 k4 = *(const float4*)(&eqk[buf][1][j]);
        ekr[j] = k4.x; ekr[j + 1] = k4.y; ekr[j + 2] = k4.z; ekr[j + 3] = k4.w;
        dA0 += w[j]     * q4.x;
        dA1 += w[j + 1] * q4.y;
        dA2 += w[j + 2] * q4.z;
        dA3 += w[j + 3] * q4.w;
        dB0 += w[j]     * k4.x;
        dB1 += w[j + 1] * k4.y;
        dB2 += w[j + 2] * k4.z;
        dB3 += w[j + 3] * k4.w;
      }
      // Block LDS rematerialization: ek values must stay in registers.
      asm volatile("" ::: "memory");
      float dv = rq * ((dA0 + dA1) + (dA2 + dA3)) - rk * ((dB0 + dB1) + (dB2 + dB3));
      float c = beta_c * dv * rk;
      #pragma unroll
      for (int j = 0; j < 64; j += 4) {
        w[j]     += c * ekr[j];
        w[j + 1] += c * ekr[j + 1];
        w[j + 2] += c * ekr[j + 2];
        w[j + 3] += c * ekr[j + 3];
      }
    }
  } else {
    // wave 3: beta + wb update
    const float* wbrow = wb0 + (size_t)head * DHEAD * 4 + lane * 4;
    float4 wbv = *(const float4*)wbrow;
    float xv = xrow0[lane];

    for (int t = 0; t < SLEN; ++t) {
      const int buf = t & 1;
      float xnext = 0.f;
      if (t + 1 < SLEN) xnext = xrow0[(size_t)(t + 1) * BSZ * INDIM + lane];

      float p0 = wave_sum64(wbv.x * xv);
      float p1 = wave_sum64(wbv.y * xv);
      float p2 = wave_sum64(wbv.z * xv);
      float p3 = wave_sum64(wbv.w * xv);
      float b0 = __fdividef(1.f, 1.f + __expf(-p0));
      float b1 = __fdividef(1.f, 1.f + __expf(-p1));
      float b2 = __fdividef(1.f, 1.f + __expf(-p2));
      float b3 = __fdividef(1.f, 1.f + __expf(-p3));
      if (lane == 0) {
        betabuf[buf][0] = b0; betabuf[buf][1] = b1;
        betabuf[buf][2] = b2; betabuf[buf][3] = b3;
      }
      __syncthreads();

      float rq = __fdividef(1.f, sbuf[buf][0]);
      float rk = __fdividef(1.f, sbuf[buf][1]);
      float qv = rq * eqk[buf][0][lane];
      float kv = rk * eqk[buf][1][lane];
      float qmk = qv - kv;
      float g0 = wave_sum64(wbv.x * qmk);
      float g1 = wave_sum64(wbv.y * qmk);
      float g2 = wave_sum64(wbv.z * qmk);
      float g3 = wave_sum64(wbv.w * qmk);
      float cl = b3 * kv;
      wbv.x += cl * g0; wbv.y += cl * g1; wbv.z += cl * g2; wbv.w += cl * g3;
      xv = xnext;
    }
  }
}

// --------------------------------------------------------------------------
// GEMM + LN epilogue: out = ys_bf16 @ out_w_bf16^T + LN(h)
// M=2048, N=1024, K=1024. 256 blocks: 128x64 tile, 2x2 waves of 64x32.
// Manual double-buffered fragment prefetch.
// --------------------------------------------------------------------------
__global__ __launch_bounds__(256, 1) void gemm_ln_k(
    const unsigned short* __restrict__ A,
    const unsigned short* __restrict__ B,
    const float* __restrict__ h,
    const float* __restrict__ stats,
    const float* __restrict__ gamma,
    const float* __restrict__ lbeta,
    float* __restrict__ out) {
  const int bx = blockIdx.x & 15;   // N tile (1024/64)
  const int by = blockIdx.x >> 4;   // M tile (2048/128)
  const int tid = threadIdx.x;
  const int wave = tid >> 6, lane = tid & 63;
  const int wr = wave >> 1, wc = wave & 1;
  const int rbase = by * 128 + wr * 64;
  const int nbase = bx * 64 + wc * 32;
  const int l16 = lane & 15;
  const int kofs = (lane >> 4) * 8;

  const short* Ap = (const short*)A;
  const short* Bp = (const short*)B;

  f32x4 acc[4][2];
  #pragma unroll
  for (int i = 0; i < 4; ++i)
    #pragma unroll
    for (int j = 0; j < 2; ++j)
      acc[i][j] = (f32x4){0.f, 0.f, 0.f, 0.f};

  const short* arow[4];
  const short* brow[2];
  #pragma unroll
  for (int i = 0; i < 4; ++i)
    arow[i] = Ap + (size_t)(rbase + i * 16 + l16) * INDIM + kofs;
  #pragma unroll
  for (int j = 0; j < 2; ++j)
    brow[j] = Bp + (size_t)(nbase + j * 16 + l16) * INDIM + kofs;

  bf16x8 a0[4], b0[2], a1[4], b1[2];
  #pragma unroll
  for (int i = 0; i < 4; ++i) a0[i] = *(const bf16x8*)(arow[i]);
  #pragma unroll
  for (int j = 0; j < 2; ++j) b0[j] = *(const bf16x8*)(brow[j]);

  for (int kk = 0; kk < INDIM; kk += 64) {
    // prefetch kk+32 (always in range: kk<=960 -> kk+32<=992)
    #pragma unroll
    for (int i = 0; i < 4; ++i) a1[i] = *(const bf16x8*)(arow[i] + kk + 32);
    #pragma unroll
    for (int j = 0; j < 2; ++j) b1[j] = *(const bf16x8*)(brow[j] + kk + 32);
    #pragma unroll
    for (int i = 0; i < 4; ++i)
      #pragma unroll
      for (int j = 0; j < 2; ++j)
        acc[i][j] = __builtin_amdgcn_mfma_f32_16x16x32_bf16(a0[i], b0[j], acc[i][j], 0, 0, 0);
    // prefetch kk+64
    if (kk + 64 < INDIM) {
      #pragma unroll
      for (int i = 0; i < 4; ++i) a0[i] = *(const bf16x8*)(arow[i] + kk + 64);
      #pragma unroll
      for (int j = 0; j < 2; ++j) b0[j] = *(const bf16x8*)(brow[j] + kk + 64);
    }
    #pragma unroll
    for (int i = 0; i < 4; ++i)
      #pragma unroll
      for (int j = 0; j < 2; ++j)
        acc[i][j] = __builtin_amdgcn_mfma_f32_16x16x32_bf16(a1[i], b1[j], acc[i][j], 0, 0, 0);
  }

  const int rq4 = (lane >> 4) * 4;
  #pragma unroll
  for (int i = 0; i < 4; ++i) {
    #pragma unroll
    for (int reg = 0; reg < 4; ++reg) {
      int r = rbase + i * 16 + rq4 + reg;
      float mu = stats[2 * r], rs = stats[2 * r + 1];
      #pragma unroll
      for (int j = 0; j < 2; ++j) {
        int n = nbase + j * 16 + l16;
        float hv = h[(size_t)r * INDIM + n];
        float hln = (hv - mu) * rs * gamma[n] + lbeta[n];
        out[(size_t)r * INDIM + n] = acc[i][j][reg] + hln;
      }
    }
  }
}

// --------------------------------------------------------------------------
extern "C" void kernel_launch(void* const* d_in, const int* in_sizes, int n_in,
                              void* d_out, int out_size, void* d_ws, size_t ws_size,
                              hipStream_t stream) {
  const float* h    = (const float*)d_in[0];
  const float* Wy   = (const float*)d_in[1];
  const float* Wq   = (const float*)d_in[2];
  const float* Wk   = (const float*)d_in[3];
  const float* wb   = (const float*)d_in[4];
  const float* outw = (const float*)d_in[5];
  const float* gam  = (const float*)d_in[6];
  const float* bet  = (const float*)d_in[7];
  float* out = (float*)d_out;

  char* ws = (char*)d_ws;
  unsigned short* ys_bf   = (unsigned short*)ws;                                  // 4 MB
  unsigned short* outw_bf = (unsigned short*)(ws + (size_t)2048 * 1024 * 2);      // 2 MB
  float* stats            = (float*)(ws + (size_t)2048 * 1024 * 2 + (size_t)1024 * 1024 * 2);

  scan_prep_k<<<128 + 1024 + 2048, 256, 0, stream>>>(h, Wy, Wq, Wk, wb, outw,
                                                     outw_bf, stats, ys_bf);
  gemm_ln_k<<<256, 256, 0, stream>>>(ys_bf, outw_bf, h, stats, gam, bet, out);
}

// Round 4
// 423.808 us; speedup vs baseline: 1.3641x; 1.3641x over previous
//
#include <hip/hip_runtime.h>
#include <hip/hip_bf16.h>

#define SLEN  256
#define BSZ   8
#define NHEAD 16
#define DHEAD 64
#define INDIM 1024
#define LN_EPS 1e-5f

typedef __attribute__((ext_vector_type(4))) float f32x4;
typedef __attribute__((ext_vector_type(8))) short bf16x8;

__device__ __forceinline__ int f_as_i(float f) { union { float f; int i; } u; u.f = f; return u.i; }
__device__ __forceinline__ float i_as_f(int i) { union { float f; int i; } u; u.i = i; return u.f; }
__device__ __forceinline__ float bflo(unsigned int u) { return i_as_f((int)(u << 16)); }
__device__ __forceinline__ float bfhi(unsigned int u) { return i_as_f((int)(u & 0xFFFF0000u)); }

__device__ inline unsigned short f2bf(float x) {
  __hip_bfloat16 b = __float2bfloat16(x);
  union { __hip_bfloat16 b; unsigned short u; } cv;
  cv.b = b;
  return cv.u;
}

// DPP move, invalid lanes -> 0 (for sum)
template <int CTRL>
__device__ __forceinline__ float dpp0(float x) {
  return i_as_f(__builtin_amdgcn_update_dpp(0, f_as_i(x), CTRL, 0xF, 0xF, true));
}

__device__ __forceinline__ float wave_sum64(float v) {
  v += dpp0<0x111>(v);
  v += dpp0<0x112>(v);
  v += dpp0<0x114>(v);
  v += dpp0<0x118>(v);
  v += dpp0<0x142>(v);  // row_bcast:15
  v += dpp0<0x143>(v);  // row_bcast:31
  return i_as_f(__builtin_amdgcn_readlane(f_as_i(v), 63));
}

// --------------------------------------------------------------------------
// Fused kernel: blocks 0..127 = SRWM scan (one chain each);
// blocks 128..1151 = out_w fp32->bf16; blocks 1152..3199 = LN row stats.
// --------------------------------------------------------------------------
__global__ __launch_bounds__(256, 1) void scan_prep_k(
    const float* __restrict__ h,
    const float* __restrict__ Wy0,
    const float* __restrict__ Wq0,
    const float* __restrict__ Wk0,
    const float* __restrict__ wb0,
    const float* __restrict__ outw,
    unsigned short* __restrict__ outw_bf,
    float* __restrict__ stats,
    unsigned short* __restrict__ ys_bf) {
  const int bid = blockIdx.x;
  const int tid = threadIdx.x;

  if (bid >= 128) {
    const int pb = bid - 128;
    if (pb < 1024) {
      int i = (pb * 256 + tid) * 4;
      float4 v = *(const float4*)(outw + i);
      ushort4 o;
      o.x = f2bf(v.x); o.y = f2bf(v.y); o.z = f2bf(v.z); o.w = f2bf(v.w);
      *(ushort4*)(outw_bf + i) = o;
    } else {
      int r = pb - 1024;
      const float* row = h + (size_t)r * INDIM;
      float4 v = *(const float4*)(row + tid * 4);
      float s  = v.x + v.y + v.z + v.w;
      float s2 = v.x * v.x + v.y * v.y + v.z * v.z + v.w * v.w;
      s  = wave_sum64(s);
      s2 = wave_sum64(s2);
      __shared__ float ls[4], ls2[4];
      int wv = tid >> 6;
      if ((tid & 63) == 0) { ls[wv] = s; ls2[wv] = s2; }
      __syncthreads();
      if (tid == 0) {
        float S  = ls[0] + ls[1] + ls[2] + ls[3];
        float S2 = ls2[0] + ls2[1] + ls2[2] + ls2[3];
        float mu = S * (1.0f / INDIM);
        float var = S2 * (1.0f / INDIM) - mu * mu;
        stats[2 * r]     = mu;
        stats[2 * r + 1] = rsqrtf(var + LN_EPS);
      }
    }
    return;
  }

  // ---------------- SRWM scan: one chain per block ----------------
  const int chain = bid;
  const int b    = chain >> 4;
  const int head = chain & 15;
  const int wv   = __builtin_amdgcn_readfirstlane(tid >> 6);
  const int lane = tid & 63;

  __shared__ __align__(16) unsigned short qh[2][64];  // bf16(exp(vq))
  __shared__ __align__(16) unsigned short kh[2][64];  // bf16(exp(vk))
  __shared__ float sbuf[2][2];                        // [buf][{q,k}] sums
  __shared__ float betabuf[2][4];

  const float* xrow0 = h + (size_t)b * INDIM + head * DHEAD;  // wave-uniform base

  if (wv < 3) {
    const float* Wsel = (wv == 0) ? Wy0 : ((wv == 1) ? Wq0 : Wk0);
    const float* wrow = Wsel + (size_t)head * DHEAD * DHEAD + (size_t)lane * DHEAD;
    float w[64];
    #pragma unroll
    for (int j = 0; j < 64; j += 4) {
      float4 t4 = *(const float4*)(wrow + j);
      w[j] = t4.x; w[j + 1] = t4.y; w[j + 2] = t4.z; w[j + 3] = t4.w;
    }
    // x_0 via wave-uniform (scalar) loads
    float xs[64];
    #pragma unroll
    for (int j = 0; j < 64; ++j) xs[j] = xrow0[j];

    for (int t = 0; t < SLEN; ++t) {
      const int buf = t & 1;
      // ---- matvec: v = W x_t (x broadcast free via SGPRs) ----
      float a0 = 0.f, a1 = 0.f, a2 = 0.f, a3 = 0.f;
      #pragma unroll
      for (int j = 0; j < 64; j += 4) {
        a0 += w[j]     * xs[j];
        a1 += w[j + 1] * xs[j + 1];
        a2 += w[j + 2] * xs[j + 2];
        a3 += w[j + 3] * xs[j + 3];
      }
      float v = (a0 + a1) + (a2 + a3);

      if (wv == 0) {
        ys_bf[(size_t)(t * BSZ + b) * INDIM + head * DHEAD + lane] = f2bf(v);
      } else {
        // no max-subtract (logits bounded); publish bf16-truncated exp
        float e = __expf(v);
        unsigned int ei = (unsigned int)f_as_i(e);
        unsigned short eb = (unsigned short)(ei >> 16);
        float er = i_as_f((int)(ei & 0xFFFF0000u));  // rounded-back value
        if (wv == 1) qh[buf][lane] = eb; else kh[buf][lane] = eb;
        float ss = wave_sum64(er);
        if (lane == 0) sbuf[buf][wv - 1] = ss;
      }

      // prefetch x_{t+1} (scalar loads; consumed next step)
      if (t + 1 < SLEN) {
        const float* xn = xrow0 + (size_t)(t + 1) * BSZ * INDIM;
        #pragma unroll
        for (int j = 0; j < 64; ++j) xs[j] = xn[j];
      }
      __syncthreads();

      // ---- region C: dv = rq*(W eq) - rk*(W ek); W += (beta*dv*rk) * ek ----
      float rq = __fdividef(1.f, sbuf[buf][0]);
      float rk = __fdividef(1.f, sbuf[buf][1]);
      float beta_c = betabuf[buf][wv];
      const uint4* qp4 = (const uint4*)(&qh[buf][0]);
      const uint4* kp4 = (const uint4*)(&kh[buf][0]);
      uint4 kp[8];  // packed k kept in 8 VGPR-quads (re-unpacked in update)
      float dA0 = 0.f, dA1 = 0.f, dA2 = 0.f, dA3 = 0.f;
      float dB0 = 0.f, dB1 = 0.f, dB2 = 0.f, dB3 = 0.f;
      #pragma unroll
      for (int g = 0; g < 8; ++g) {
        uint4 qv = qp4[g];
        uint4 kv = kp4[g];
        kp[g] = kv;
        const int j = g * 8;
        dA0 += w[j]     * bflo(qv.x);
        dA1 += w[j + 1] * bfhi(qv.x);
        dA2 += w[j + 2] * bflo(qv.y);
        dA3 += w[j + 3] * bfhi(qv.y);
        dA0 += w[j + 4] * bflo(qv.z);
        dA1 += w[j + 5] * bfhi(qv.z);
        dA2 += w[j + 6] * bflo(qv.w);
        dA3 += w[j + 7] * bfhi(qv.w);
        dB0 += w[j]     * bflo(kv.x);
        dB1 += w[j + 1] * bfhi(kv.x);
        dB2 += w[j + 2] * bflo(kv.y);
        dB3 += w[j + 3] * bfhi(kv.y);
        dB0 += w[j + 4] * bflo(kv.z);
        dB1 += w[j + 5] * bfhi(kv.z);
        dB2 += w[j + 6] * bflo(kv.w);
        dB3 += w[j + 7] * bfhi(kv.w);
      }
      float dv = rq * ((dA0 + dA1) + (dA2 + dA3)) - rk * ((dB0 + dB1) + (dB2 + dB3));
      float c = beta_c * dv * rk;
      #pragma unroll
      for (int g = 0; g < 8; ++g) {
        uint4 kv = kp[g];
        const int j = g * 8;
        w[j]     += c * bflo(kv.x);
        w[j + 1] += c * bfhi(kv.x);
        w[j + 2] += c * bflo(kv.y);
        w[j + 3] += c * bfhi(kv.y);
        w[j + 4] += c * bflo(kv.z);
        w[j + 5] += c * bfhi(kv.z);
        w[j + 6] += c * bflo(kv.w);
        w[j + 7] += c * bfhi(kv.w);
      }
    }
  } else {
    // wave 3: beta + wb update
    const float* wbrow = wb0 + (size_t)head * DHEAD * 4 + lane * 4;
    float4 wbv = *(const float4*)wbrow;
    float xv = xrow0[lane];

    for (int t = 0; t < SLEN; ++t) {
      const int buf = t & 1;
      float xnext = 0.f;
      if (t + 1 < SLEN) xnext = xrow0[(size_t)(t + 1) * BSZ * INDIM + lane];

      float p0 = wave_sum64(wbv.x * xv);
      float p1 = wave_sum64(wbv.y * xv);
      float p2 = wave_sum64(wbv.z * xv);
      float p3 = wave_sum64(wbv.w * xv);
      float b0 = __fdividef(1.f, 1.f + __expf(-p0));
      float b1 = __fdividef(1.f, 1.f + __expf(-p1));
      float b2 = __fdividef(1.f, 1.f + __expf(-p2));
      float b3 = __fdividef(1.f, 1.f + __expf(-p3));
      if (lane == 0) {
        betabuf[buf][0] = b0; betabuf[buf][1] = b1;
        betabuf[buf][2] = b2; betabuf[buf][3] = b3;
      }
      __syncthreads();

      float rq = __fdividef(1.f, sbuf[buf][0]);
      float rk = __fdividef(1.f, sbuf[buf][1]);
      float qv = rq * bflo((unsigned int)qh[buf][lane] << 0) ;
      // note: qh holds the HIGH 16 bits; reconstruct via <<16
      qv = rq * i_as_f((int)((unsigned int)qh[buf][lane] << 16));
      float kv = rk * i_as_f((int)((unsigned int)kh[buf][lane] << 16));
      float qmk = qv - kv;
      float g0 = wave_sum64(wbv.x * qmk);
      float g1 = wave_sum64(wbv.y * qmk);
      float g2 = wave_sum64(wbv.z * qmk);
      float g3 = wave_sum64(wbv.w * qmk);
      float cl = b3 * kv;
      wbv.x += cl * g0; wbv.y += cl * g1; wbv.z += cl * g2; wbv.w += cl * g3;
      xv = xnext;
    }
  }
}

// --------------------------------------------------------------------------
// GEMM + LN epilogue: out = ys_bf16 @ out_w_bf16^T + LN(h)
// M=2048, N=1024, K=1024. 512 blocks: 64x64 tile, 2x2 waves of 32x32.
// 4-buffer rotation, 2 chunks (8 loads) in flight.
// --------------------------------------------------------------------------
__global__ __launch_bounds__(256, 1) void gemm_ln_k(
    const unsigned short* __restrict__ A,
    const unsigned short* __restrict__ B,
    const float* __restrict__ h,
    const float* __restrict__ stats,
    const float* __restrict__ gamma,
    const float* __restrict__ lbeta,
    float* __restrict__ out) {
  const int bx = blockIdx.x & 15;   // N tile (1024/64)
  const int by = blockIdx.x >> 4;   // M tile (2048/64) -> 0..31
  const int tid = threadIdx.x;
  const int wave = tid >> 6, lane = tid & 63;
  const int wr = wave >> 1, wc = wave & 1;
  const int rbase = by * 64 + wr * 32;
  const int nbase = bx * 64 + wc * 32;
  const int l16 = lane & 15;
  const int kofs = (lane >> 4) * 8;

  const short* Ap = (const short*)A;
  const short* Bp = (const short*)B;

  f32x4 acc[2][2];
  #pragma unroll
  for (int i = 0; i < 2; ++i)
    #pragma unroll
    for (int j = 0; j < 2; ++j)
      acc[i][j] = (f32x4){0.f, 0.f, 0.f, 0.f};

  const short* arow[2];
  const short* brow[2];
  #pragma unroll
  for (int i = 0; i < 2; ++i)
    arow[i] = Ap + (size_t)(rbase + i * 16 + l16) * INDIM + kofs;
  #pragma unroll
  for (int j = 0; j < 2; ++j)
    brow[j] = Bp + (size_t)(nbase + j * 16 + l16) * INDIM + kofs;

  // 4 rotating K-chunk buffers (chunk = 32 K-elems); depth-2 prefetch.
  bf16x8 Ab[4][2], Bb[4][2];
  #pragma unroll
  for (int i = 0; i < 2; ++i) { Ab[0][i] = *(const bf16x8*)(arow[i]);      Bb[0][i] = *(const bf16x8*)(brow[i]); }
  #pragma unroll
  for (int i = 0; i < 2; ++i) { Ab[1][i] = *(const bf16x8*)(arow[i] + 32); Bb[1][i] = *(const bf16x8*)(brow[i] + 32); }

  for (int n8 = 0; n8 < 8; ++n8) {
    #pragma unroll
    for (int c = 0; c < 4; ++c) {
      const int n = n8 * 4 + c;
      if (n + 2 < 32) {
        const int kk = (n + 2) * 32;
        const int pb = (c + 2) & 3;
        #pragma unroll
        for (int i = 0; i < 2; ++i) {
          Ab[pb][i] = *(const bf16x8*)(arow[i] + kk);
          Bb[pb][i] = *(const bf16x8*)(brow[i] + kk);
        }
      }
      #pragma unroll
      for (int i = 0; i < 2; ++i)
        #pragma unroll
        for (int j = 0; j < 2; ++j)
          acc[i][j] = __builtin_amdgcn_mfma_f32_16x16x32_bf16(Ab[c][i], Bb[c][j], acc[i][j], 0, 0, 0);
    }
  }

  const int rq4 = (lane >> 4) * 4;
  #pragma unroll
  for (int i = 0; i < 2; ++i) {
    #pragma unroll
    for (int reg = 0; reg < 4; ++reg) {
      int r = rbase + i * 16 + rq4 + reg;
      float mu = stats[2 * r], rs = stats[2 * r + 1];
      #pragma unroll
      for (int j = 0; j < 2; ++j) {
        int n = nbase + j * 16 + l16;
        float hv = h[(size_t)r * INDIM + n];
        float hln = (hv - mu) * rs * gamma[n] + lbeta[n];
        out[(size_t)r * INDIM + n] = acc[i][j][reg] + hln;
      }
    }
  }
}

// --------------------------------------------------------------------------
extern "C" void kernel_launch(void* const* d_in, const int* in_sizes, int n_in,
                              void* d_out, int out_size, void* d_ws, size_t ws_size,
                              hipStream_t stream) {
  const float* h    = (const float*)d_in[0];
  const float* Wy   = (const float*)d_in[1];
  const float* Wq   = (const float*)d_in[2];
  const float* Wk   = (const float*)d_in[3];
  const float* wb   = (const float*)d_in[4];
  const float* outw = (const float*)d_in[5];
  const float* gam  = (const float*)d_in[6];
  const float* bet  = (const float*)d_in[7];
  float* out = (float*)d_out;

  char* ws = (char*)d_ws;
  unsigned short* ys_bf   = (unsigned short*)ws;                                  // 4 MB
  unsigned short* outw_bf = (unsigned short*)(ws + (size_t)2048 * 1024 * 2);      // 2 MB
  float* stats            = (float*)(ws + (size_t)2048 * 1024 * 2 + (size_t)1024 * 1024 * 2);

  scan_prep_k<<<128 + 1024 + 2048, 256, 0, stream>>>(h, Wy, Wq, Wk, wb, outw,
                                                     outw_bf, stats, ys_bf);
  gemm_ln_k<<<512, 256, 0, stream>>>(ys_bf, outw_bf, h, stats, gam, bet, out);
}

// Round 5
// 357.088 us; speedup vs baseline: 1.6190x; 1.1868x over previous
//
#include <hip/hip_runtime.h>
#include <hip/hip_bf16.h>

#define SLEN  256
#define BSZ   8
#define NHEAD 16
#define DHEAD 64
#define INDIM 1024
#define LN_EPS 1e-5f

typedef __attribute__((ext_vector_type(4))) float f32x4;
typedef __attribute__((ext_vector_type(8))) short bf16x8;

__device__ __forceinline__ int f_as_i(float f) { union { float f; int i; } u; u.f = f; return u.i; }
__device__ __forceinline__ float i_as_f(int i) { union { float f; int i; } u; u.i = i; return u.f; }

__device__ inline unsigned short f2bf(float x) {
  __hip_bfloat16 b = __float2bfloat16(x);
  union { __hip_bfloat16 b; unsigned short u; } cv;
  cv.b = b;
  return cv.u;
}

// DPP move, invalid lanes -> 0 (all patterns used are full-wave-valid)
template <int CTRL>
__device__ __forceinline__ float dpp0(float x) {
  return i_as_f(__builtin_amdgcn_update_dpp(0, f_as_i(x), CTRL, 0xF, 0xF, true));
}

// adjacent-lane pair swap: quad_perm [1,0,3,2] = 0xB1
__device__ __forceinline__ float pair_other(float x) { return dpp0<0xB1>(x); }

__device__ __forceinline__ float wave_sum64(float v) {
  v += dpp0<0x111>(v);  // row_shr:1
  v += dpp0<0x112>(v);  // row_shr:2
  v += dpp0<0x114>(v);  // row_shr:4
  v += dpp0<0x118>(v);  // row_shr:8
  v += dpp0<0x142>(v);  // row_bcast:15
  v += dpp0<0x143>(v);  // row_bcast:31
  return i_as_f(__builtin_amdgcn_readlane(f_as_i(v), 63));
}

// --------------------------------------------------------------------------
// Fused kernel (512 threads/block):
//   blocks 0..127     : SRWM scan, one chain per block, 8 waves
//   blocks 128..639   : out_w fp32->bf16 (512 blocks x 2048 elems)
//   blocks 640..2687  : LN row stats (2048 rows)
// --------------------------------------------------------------------------
__global__ __launch_bounds__(512, 1) void scan_prep_k(
    const float* __restrict__ h,
    const float* __restrict__ Wy0,
    const float* __restrict__ Wq0,
    const float* __restrict__ Wk0,
    const float* __restrict__ wb0,
    const float* __restrict__ outw,
    unsigned short* __restrict__ outw_bf,
    float* __restrict__ stats,
    unsigned short* __restrict__ ys_bf) {
  const int bid = blockIdx.x;
  const int tid = threadIdx.x;

  if (bid >= 128) {
    const int pb = bid - 128;
    if (pb < 512) {
      int i = (pb * 512 + tid) * 4;
      float4 v = *(const float4*)(outw + i);
      ushort4 o;
      o.x = f2bf(v.x); o.y = f2bf(v.y); o.z = f2bf(v.z); o.w = f2bf(v.w);
      *(ushort4*)(outw_bf + i) = o;
    } else {
      int r = pb - 512;  // 0..2047
      const float* row = h + (size_t)r * INDIM;
      float2 v = *(const float2*)(row + tid * 2);
      float s  = v.x + v.y;
      float s2 = v.x * v.x + v.y * v.y;
      s  = wave_sum64(s);
      s2 = wave_sum64(s2);
      __shared__ float ls[8], ls2[8];
      int wvv = tid >> 6;
      if ((tid & 63) == 0) { ls[wvv] = s; ls2[wvv] = s2; }
      __syncthreads();
      if (tid == 0) {
        float S = 0.f, S2 = 0.f;
        #pragma unroll
        for (int i = 0; i < 8; ++i) { S += ls[i]; S2 += ls2[i]; }
        float mu = S * (1.0f / INDIM);
        float var = S2 * (1.0f / INDIM) - mu * mu;
        stats[2 * r]     = mu;
        stats[2 * r + 1] = rsqrtf(var + LN_EPS);
      }
    }
    return;
  }

  // ---------------- SRWM scan: one chain per block, 8 waves ----------------
  // waves 0..5: matrix waves; m = wv>>1 (0=Wy,1=Wq,2=Wk), half = wv&1
  //   lane pair (2p,2p+1) owns row r = half*32+p; lane&1 selects column half.
  // wave 6: wb / beta
  // wave 7: x staging (global -> LDS, depth-2 pipelined)
  const int chain = bid;
  const int b    = chain >> 4;
  const int head = chain & 15;
  const int wv   = __builtin_amdgcn_readfirstlane(tid >> 6);
  const int lane = tid & 63;

  __shared__ __align__(16) float xbuf[2][64];
  __shared__ __align__(16) float eqk[2][2][64];   // [buf][{q,k}][row] = exp(v)
  __shared__ __align__(16) float ssub[2][4];      // [buf][{q0,q1,k0,k1}] partial sums
  __shared__ __align__(16) float betabuf[2][4];

  const float* xrow0 = h + (size_t)b * INDIM + head * DHEAD;

  if (wv < 6) {
    const int m    = wv >> 1;
    const int half = wv & 1;
    const int r    = half * 32 + (lane >> 1);
    const int j0   = (lane & 1) * 32;
    const float* Wsel = (m == 0) ? Wy0 : ((m == 1) ? Wq0 : Wk0);
    const float* wrow = Wsel + (size_t)head * DHEAD * DHEAD + (size_t)r * DHEAD + j0;
    float w[32];
    #pragma unroll
    for (int g = 0; g < 8; ++g) {
      float4 t4 = *(const float4*)(wrow + g * 4);
      w[g * 4] = t4.x; w[g * 4 + 1] = t4.y; w[g * 4 + 2] = t4.z; w[g * 4 + 3] = t4.w;
    }
    __syncthreads();  // prologue: xbuf[0] staged by wave 7

    for (int t = 0; t < SLEN; ++t) {
      const int buf = t & 1;
      // ---- half-row matvec: v_partial = sum_j W[r][j0+j] * x[j0+j] ----
      float a0 = 0.f, a1 = 0.f, a2 = 0.f, a3 = 0.f;
      #pragma unroll
      for (int g = 0; g < 8; ++g) {
        float4 x4 = *(const float4*)(&xbuf[buf][j0 + g * 4]);
        a0 += w[g * 4]     * x4.x;
        a1 += w[g * 4 + 1] * x4.y;
        a2 += w[g * 4 + 2] * x4.z;
        a3 += w[g * 4 + 3] * x4.w;
      }
      float v = (a0 + a1) + (a2 + a3);
      v += pair_other(v);  // full row dot in both pair lanes

      if (m == 0) {
        if (!(lane & 1))
          ys_bf[(size_t)(t * BSZ + b) * INDIM + head * DHEAD + r] = f2bf(v);
      } else {
        float e = __expf(v);   // logits bounded; no max-subtract needed
        if (!(lane & 1)) eqk[buf][m - 1][r] = e;
        float sh = wave_sum64(e) * 0.5f;  // rows duplicated across pair lanes
        if (lane == 0) ssub[buf][(m - 1) * 2 + half] = sh;
      }
      __syncthreads();

      // ---- dv = rq*(W eq) - rk*(W ek); W += (beta*dv*rk) * ek ----
      float4 ss = *(const float4*)(&ssub[buf][0]);
      float rq = __fdividef(1.f, ss.x + ss.y);
      float rk = __fdividef(1.f, ss.z + ss.w);
      float bet = betabuf[buf][m];
      float ek[32];
      float dq0 = 0.f, dq1 = 0.f, dq2 = 0.f, dq3 = 0.f;
      float dk0 = 0.f, dk1 = 0.f, dk2 = 0.f, dk3 = 0.f;
      #pragma unroll
      for (int g = 0; g < 8; ++g) {
        float4 q4 = *(const float4*)(&eqk[buf][0][j0 + g * 4]);
        float4 k4 = *(const float4*)(&eqk[buf][1][j0 + g * 4]);
        ek[g * 4] = k4.x; ek[g * 4 + 1] = k4.y; ek[g * 4 + 2] = k4.z; ek[g * 4 + 3] = k4.w;
        dq0 += w[g * 4]     * q4.x;
        dq1 += w[g * 4 + 1] * q4.y;
        dq2 += w[g * 4 + 2] * q4.z;
        dq3 += w[g * 4 + 3] * q4.w;
        dk0 += w[g * 4]     * k4.x;
        dk1 += w[g * 4 + 1] * k4.y;
        dk2 += w[g * 4 + 2] * k4.z;
        dk3 += w[g * 4 + 3] * k4.w;
      }
      float dv = rq * ((dq0 + dq1) + (dq2 + dq3)) - rk * ((dk0 + dk1) + (dk2 + dk3));
      dv += pair_other(dv);  // full-row dv in both pair lanes
      float c = bet * dv * rk;
      #pragma unroll
      for (int g = 0; g < 8; ++g) {
        w[g * 4]     += c * ek[g * 4];
        w[g * 4 + 1] += c * ek[g * 4 + 1];
        w[g * 4 + 2] += c * ek[g * 4 + 2];
        w[g * 4 + 3] += c * ek[g * 4 + 3];
      }
    }
  } else if (wv == 6) {
    // wb / beta wave
    const float* wbrow = wb0 + (size_t)head * DHEAD * 4 + lane * 4;
    float4 wbv = *(const float4*)wbrow;
    __syncthreads();  // prologue

    for (int t = 0; t < SLEN; ++t) {
      const int buf = t & 1;
      float xv = xbuf[buf][lane];
      float p0 = wave_sum64(wbv.x * xv);
      float p1 = wave_sum64(wbv.y * xv);
      float p2 = wave_sum64(wbv.z * xv);
      float p3 = wave_sum64(wbv.w * xv);
      float b0 = __fdividef(1.f, 1.f + __expf(-p0));
      float b1 = __fdividef(1.f, 1.f + __expf(-p1));
      float b2 = __fdividef(1.f, 1.f + __expf(-p2));
      float b3 = __fdividef(1.f, 1.f + __expf(-p3));
      if (lane == 0) {
        *(float4*)(&betabuf[buf][0]) = (float4){b0, b1, b2, b3};
      }
      __syncthreads();

      float4 ss = *(const float4*)(&ssub[buf][0]);
      float rq = __fdividef(1.f, ss.x + ss.y);
      float rk = __fdividef(1.f, ss.z + ss.w);
      float qv = rq * eqk[buf][0][lane];
      float kv = rk * eqk[buf][1][lane];
      float qmk = qv - kv;
      float g0 = wave_sum64(wbv.x * qmk);
      float g1 = wave_sum64(wbv.y * qmk);
      float g2 = wave_sum64(wbv.z * qmk);
      float g3 = wave_sum64(wbv.w * qmk);
      float cl = b3 * kv;
      wbv.x += cl * g0; wbv.y += cl * g1; wbv.z += cl * g2; wbv.w += cl * g3;
    }
  } else {
    // wave 7: x staging with depth-2 register pipeline
    float x0 = xrow0[lane];
    xbuf[0][lane] = x0;
    float xn1 = xrow0[(size_t)1 * BSZ * INDIM + lane];  // x_1
    __syncthreads();  // prologue

    for (int t = 0; t < SLEN; ++t) {
      if (t + 1 < SLEN) xbuf[(t + 1) & 1][lane] = xn1;  // write x_{t+1}
      float xn2 = 0.f;
      if (t + 2 < SLEN) xn2 = xrow0[(size_t)(t + 2) * BSZ * INDIM + lane];
      __syncthreads();
      xn1 = xn2;
    }
  }
}

// --------------------------------------------------------------------------
// GEMM + LN epilogue: out = ys_bf16 @ out_w_bf16^T + LN(h)
// M=2048, N=1024, K=1024. 1024 blocks: 32x64 tile, 2x2 waves of 16x32.
// 4 blocks/CU -> 16 waves/CU for TLP latency hiding; depth-2 chunk rotation.
// --------------------------------------------------------------------------
__global__ __launch_bounds__(256, 1) void gemm_ln_k(
    const unsigned short* __restrict__ A,
    const unsigned short* __restrict__ B,
    const float* __restrict__ h,
    const float* __restrict__ stats,
    const float* __restrict__ gamma,
    const float* __restrict__ lbeta,
    float* __restrict__ out) {
  const int bx = blockIdx.x & 15;   // N tile (1024/64)
  const int by = blockIdx.x >> 4;   // M tile (2048/32) -> 0..63
  const int tid = threadIdx.x;
  const int wave = tid >> 6, lane = tid & 63;
  const int wr = wave >> 1, wc = wave & 1;
  const int rbase = by * 32 + wr * 16;
  const int nbase = bx * 64 + wc * 32;
  const int l16 = lane & 15;
  const int kofs = (lane >> 4) * 8;

  const short* Ap = (const short*)A;
  const short* Bp = (const short*)B;

  f32x4 acc[2];
  acc[0] = (f32x4){0.f, 0.f, 0.f, 0.f};
  acc[1] = (f32x4){0.f, 0.f, 0.f, 0.f};

  const short* arow = Ap + (size_t)(rbase + l16) * INDIM + kofs;
  const short* brow[2];
  #pragma unroll
  for (int j = 0; j < 2; ++j)
    brow[j] = Bp + (size_t)(nbase + j * 16 + l16) * INDIM + kofs;

  bf16x8 Ab[4], Bb[4][2];
  Ab[0] = *(const bf16x8*)(arow);
  Ab[1] = *(const bf16x8*)(arow + 32);
  #pragma unroll
  for (int j = 0; j < 2; ++j) {
    Bb[0][j] = *(const bf16x8*)(brow[j]);
    Bb[1][j] = *(const bf16x8*)(brow[j] + 32);
  }

  for (int n8 = 0; n8 < 8; ++n8) {
    #pragma unroll
    for (int c = 0; c < 4; ++c) {
      const int n = n8 * 4 + c;
      if (n + 2 < 32) {
        const int kk = (n + 2) * 32;
        const int pb = (c + 2) & 3;
        Ab[pb] = *(const bf16x8*)(arow + kk);
        #pragma unroll
        for (int j = 0; j < 2; ++j)
          Bb[pb][j] = *(const bf16x8*)(brow[j] + kk);
      }
      #pragma unroll
      for (int j = 0; j < 2; ++j)
        acc[j] = __builtin_amdgcn_mfma_f32_16x16x32_bf16(Ab[c & 3], Bb[c & 3][j], acc[j], 0, 0, 0);
    }
  }

  const int rq4 = (lane >> 4) * 4;
  #pragma unroll
  for (int reg = 0; reg < 4; ++reg) {
    int r = rbase + rq4 + reg;
    float mu = stats[2 * r], rs = stats[2 * r + 1];
    #pragma unroll
    for (int j = 0; j < 2; ++j) {
      int n = nbase + j * 16 + l16;
      float hv = h[(size_t)r * INDIM + n];
      float hln = (hv - mu) * rs * gamma[n] + lbeta[n];
      out[(size_t)r * INDIM + n] = acc[j][reg] + hln;
    }
  }
}

// --------------------------------------------------------------------------
extern "C" void kernel_launch(void* const* d_in, const int* in_sizes, int n_in,
                              void* d_out, int out_size, void* d_ws, size_t ws_size,
                              hipStream_t stream) {
  const float* h    = (const float*)d_in[0];
  const float* Wy   = (const float*)d_in[1];
  const float* Wq   = (const float*)d_in[2];
  const float* Wk   = (const float*)d_in[3];
  const float* wb   = (const float*)d_in[4];
  const float* outw = (const float*)d_in[5];
  const float* gam  = (const float*)d_in[6];
  const float* bet  = (const float*)d_in[7];
  float* out = (float*)d_out;

  char* ws = (char*)d_ws;
  unsigned short* ys_bf   = (unsigned short*)ws;                                  // 4 MB
  unsigned short* outw_bf = (unsigned short*)(ws + (size_t)2048 * 1024 * 2);      // 2 MB
  float* stats            = (float*)(ws + (size_t)2048 * 1024 * 2 + (size_t)1024 * 1024 * 2);

  scan_prep_k<<<128 + 512 + 2048, 512, 0, stream>>>(h, Wy, Wq, Wk, wb, outw,
                                                    outw_bf, stats, ys_bf);
  gemm_ln_k<<<1024, 256, 0, stream>>>(ys_bf, outw_bf, h, stats, gam, bet, out);
}

// Round 6
// 347.945 us; speedup vs baseline: 1.6616x; 1.0263x over previous
//
#include <hip/hip_runtime.h>
#include <hip/hip_bf16.h>

#define SLEN  256
#define BSZ   8
#define NHEAD 16
#define DHEAD 64
#define INDIM 1024
#define LN_EPS 1e-5f

typedef __attribute__((ext_vector_type(4))) float f32x4;
typedef __attribute__((ext_vector_type(8))) short bf16x8;

__device__ __forceinline__ int f_as_i(float f) { union { float f; int i; } u; u.f = f; return u.i; }
__device__ __forceinline__ float i_as_f(int i) { union { float f; int i; } u; u.i = i; return u.f; }

__device__ inline unsigned short f2bf(float x) {
  __hip_bfloat16 b = __float2bfloat16(x);
  union { __hip_bfloat16 b; unsigned short u; } cv;
  cv.b = b;
  return cv.u;
}

template <int CTRL>
__device__ __forceinline__ float dpp0(float x) {
  return i_as_f(__builtin_amdgcn_update_dpp(0, f_as_i(x), CTRL, 0xF, 0xF, true));
}
// adjacent-lane pair swap: quad_perm [1,0,3,2]
__device__ __forceinline__ float pair_other(float x) { return dpp0<0xB1>(x); }

__device__ __forceinline__ float wave_sum64(float v) {
  v += dpp0<0x111>(v);
  v += dpp0<0x112>(v);
  v += dpp0<0x114>(v);
  v += dpp0<0x118>(v);
  v += dpp0<0x142>(v);  // row_bcast:15
  v += dpp0<0x143>(v);  // row_bcast:31
  return i_as_f(__builtin_amdgcn_readlane(f_as_i(v), 63));
}

// --------------------------------------------------------------------------
// Fused kernel (512 threads/block):
//   blocks 0..127     : SRWM scan, one chain per block, 8 waves
//   blocks 128..639   : out_w fp32->bf16
//   blocks 640..2687  : LN stats + write h_ln into d_out
// --------------------------------------------------------------------------
__global__ __launch_bounds__(512, 2) void scan_prep_k(
    const float* __restrict__ h,
    const float* __restrict__ Wy0,
    const float* __restrict__ Wq0,
    const float* __restrict__ Wk0,
    const float* __restrict__ wb0,
    const float* __restrict__ outw,
    const float* __restrict__ gamma,
    const float* __restrict__ lbeta,
    unsigned short* __restrict__ outw_bf,
    float* __restrict__ outp,
    unsigned short* __restrict__ ys_bf) {
  const int bid = blockIdx.x;
  const int tid = threadIdx.x;

  if (bid >= 128) {
    const int pb = bid - 128;
    if (pb < 512) {
      int i = (pb * 512 + tid) * 4;
      float4 v = *(const float4*)(outw + i);
      ushort4 o;
      o.x = f2bf(v.x); o.y = f2bf(v.y); o.z = f2bf(v.z); o.w = f2bf(v.w);
      *(ushort4*)(outw_bf + i) = o;
    } else {
      int r = pb - 512;  // 0..2047
      const float* row = h + (size_t)r * INDIM;
      float2 v = *(const float2*)(row + tid * 2);
      float s  = v.x + v.y;
      float s2 = v.x * v.x + v.y * v.y;
      s  = wave_sum64(s);
      s2 = wave_sum64(s2);
      __shared__ float ls[8], ls2[8], sstat[2];
      int wvv = tid >> 6;
      if ((tid & 63) == 0) { ls[wvv] = s; ls2[wvv] = s2; }
      __syncthreads();
      if (tid == 0) {
        float S = 0.f, S2 = 0.f;
        #pragma unroll
        for (int i = 0; i < 8; ++i) { S += ls[i]; S2 += ls2[i]; }
        float mu = S * (1.0f / INDIM);
        float var = S2 * (1.0f / INDIM) - mu * mu;
        sstat[0] = mu;
        sstat[1] = rsqrtf(var + LN_EPS);
      }
      __syncthreads();
      float mu = sstat[0], rs = sstat[1];
      float2 g2 = *(const float2*)(gamma + tid * 2);
      float2 b2 = *(const float2*)(lbeta + tid * 2);
      float2 o;
      o.x = (v.x - mu) * rs * g2.x + b2.x;
      o.y = (v.y - mu) * rs * g2.y + b2.y;
      *(float2*)(outp + (size_t)r * INDIM + tid * 2) = o;
    }
    return;
  }

  // ---------------- SRWM scan: one chain per block, 8 waves ----------------
  // waves 0..5: matrix waves, m=wv>>1 (0=Wy,1=Wq,2=Wk), half=wv&1;
  //   lane pair (2p,2p+1) owns row r=half*32+p; lane&1 picks 32-col half.
  // wave 6: wb / beta.  wave 7: x staging (global->LDS, 3 steps ahead).
  const int chain = bid;
  const int b    = chain >> 4;
  const int head = chain & 15;
  const int wv   = __builtin_amdgcn_readfirstlane(tid >> 6);
  const int lane = tid & 63;

  __shared__ __align__(16) float xbuf[3][64];      // x_t in slot t%3
  __shared__ __align__(16) float eqk[2][2][64];    // [t&1][{q,k}][row] = exp(v)
  __shared__ __align__(16) float ssub[2][4];       // [t&1][{q0,q1,k0,k1}]
  __shared__ __align__(16) float betabuf[2][4];    // [t&1][4]

  const float* xrow0 = h + (size_t)b * INDIM + head * DHEAD;

#define PUBLISH(T, V) {                                                          \
    if (m == 0) {                                                                \
      if (!(lane & 1))                                                           \
        ys_bf[(size_t)((T) * BSZ + b) * INDIM + head * DHEAD + r] = f2bf(V);     \
    } else {                                                                     \
      float e_ = __expf(V);                                                      \
      if (!(lane & 1)) eqk[(T) & 1][m - 1][r] = e_;                              \
      float sh_ = wave_sum64(e_) * 0.5f;                                         \
      if (lane == 0) ssub[(T) & 1][(m - 1) * 2 + half] = sh_;                    \
    }                                                                            \
  }

#define PHASE(T, XC, XN) {                                                       \
    const int bp_ = ((T) - 1) & 1;                                               \
    float4 ss4 = *(const float4*)(&ssub[bp_][0]);                                \
    float4 bb4 = *(const float4*)(&betabuf[bp_][0]);                             \
    float4 q4[8], k4[8];                                                         \
    _Pragma("unroll")                                                            \
    for (int g = 0; g < 8; ++g) {                                                \
      q4[g] = *(const float4*)(&eqk[bp_][0][j0 + g * 4]);                        \
      k4[g] = *(const float4*)(&eqk[bp_][1][j0 + g * 4]);                        \
    }                                                                            \
    if ((T) + 1 < SLEN) {                                                        \
      const float* xsrc_ = &xbuf[((T) + 1) % 3][j0];                             \
      _Pragma("unroll")                                                          \
      for (int g = 0; g < 8; ++g) {                                              \
        float4 x4_ = *(const float4*)(xsrc_ + g * 4);                            \
        XN[g * 4] = x4_.x; XN[g * 4 + 1] = x4_.y;                                \
        XN[g * 4 + 2] = x4_.z; XN[g * 4 + 3] = x4_.w;                            \
      }                                                                          \
    }                                                                            \
    float dq0 = 0.f, dq1 = 0.f, dq2 = 0.f, dq3 = 0.f;                            \
    float dk0 = 0.f, dk1 = 0.f, dk2 = 0.f, dk3 = 0.f;                            \
    _Pragma("unroll")                                                            \
    for (int g = 0; g < 8; ++g) {                                                \
      dq0 += w[g * 4]     * q4[g].x; dq1 += w[g * 4 + 1] * q4[g].y;              \
      dq2 += w[g * 4 + 2] * q4[g].z; dq3 += w[g * 4 + 3] * q4[g].w;              \
      dk0 += w[g * 4]     * k4[g].x; dk1 += w[g * 4 + 1] * k4[g].y;              \
      dk2 += w[g * 4 + 2] * k4[g].z; dk3 += w[g * 4 + 3] * k4[g].w;              \
    }                                                                            \
    float rq = __fdividef(1.f, ss4.x + ss4.y);                                   \
    float rk = __fdividef(1.f, ss4.z + ss4.w);                                   \
    float dv = rq * ((dq0 + dq1) + (dq2 + dq3))                                  \
             - rk * ((dk0 + dk1) + (dk2 + dk3));                                 \
    dv += pair_other(dv);                                                        \
    float bet_ = (m == 0) ? bb4.x : ((m == 1) ? bb4.y : bb4.z);                  \
    float c_ = bet_ * dv * rk;                                                   \
    _Pragma("unroll")                                                            \
    for (int g = 0; g < 8; ++g) {                                                \
      w[g * 4]     += c_ * k4[g].x; w[g * 4 + 1] += c_ * k4[g].y;                \
      w[g * 4 + 2] += c_ * k4[g].z; w[g * 4 + 3] += c_ * k4[g].w;                \
    }                                                                            \
    float a0 = 0.f, a1 = 0.f, a2 = 0.f, a3 = 0.f;                                \
    _Pragma("unroll")                                                            \
    for (int g = 0; g < 8; ++g) {                                                \
      a0 += w[g * 4]     * XC[g * 4];     a1 += w[g * 4 + 1] * XC[g * 4 + 1];    \
      a2 += w[g * 4 + 2] * XC[g * 4 + 2]; a3 += w[g * 4 + 3] * XC[g * 4 + 3];    \
    }                                                                            \
    float v_ = (a0 + a1) + (a2 + a3);                                            \
    v_ += pair_other(v_);                                                        \
    PUBLISH(T, v_);                                                              \
    __syncthreads();                                                             \
  }

  if (wv < 6) {
    const int m    = wv >> 1;
    const int half = wv & 1;
    const int r    = half * 32 + (lane >> 1);
    const int j0   = (lane & 1) * 32;
    const float* Wsel = (m == 0) ? Wy0 : ((m == 1) ? Wq0 : Wk0);
    const float* wrow = Wsel + (size_t)head * DHEAD * DHEAD + (size_t)r * DHEAD + j0;
    float w[32];
    #pragma unroll
    for (int g = 0; g < 8; ++g) {
      float4 t4 = *(const float4*)(wrow + g * 4);
      w[g * 4] = t4.x; w[g * 4 + 1] = t4.y; w[g * 4 + 2] = t4.z; w[g * 4 + 3] = t4.w;
    }
    float xA[32], xB[32];
    #pragma unroll
    for (int g = 0; g < 8; ++g) {   // x_0 from global
      float4 t4 = *(const float4*)(xrow0 + j0 + g * 4);
      xA[g * 4] = t4.x; xA[g * 4 + 1] = t4.y; xA[g * 4 + 2] = t4.z; xA[g * 4 + 3] = t4.w;
    }
    __syncthreads();  // prologue (wave7 pre-staged x_1, x_2)

    // phase 0: matvec_0 + publish; load xB = x_1
    {
      float a0 = 0.f, a1 = 0.f, a2 = 0.f, a3 = 0.f;
      #pragma unroll
      for (int g = 0; g < 8; ++g) {
        a0 += w[g * 4]     * xA[g * 4];     a1 += w[g * 4 + 1] * xA[g * 4 + 1];
        a2 += w[g * 4 + 2] * xA[g * 4 + 2]; a3 += w[g * 4 + 3] * xA[g * 4 + 3];
      }
      float v0 = (a0 + a1) + (a2 + a3);
      v0 += pair_other(v0);
      PUBLISH(0, v0);
      #pragma unroll
      for (int g = 0; g < 8; ++g) {
        float4 x4 = *(const float4*)(&xbuf[1][j0 + g * 4]);
        xB[g * 4] = x4.x; xB[g * 4 + 1] = x4.y; xB[g * 4 + 2] = x4.z; xB[g * 4 + 3] = x4.w;
      }
      __syncthreads();
    }
    for (int tt = 1; tt <= 253; tt += 2) {
      PHASE(tt, xB, xA);
      PHASE(tt + 1, xA, xB);
    }
    PHASE(255, xB, xA);
  } else if (wv == 6) {
    // wb / beta wave
    const float* wbrow = wb0 + (size_t)head * DHEAD * 4 + lane * 4;
    float4 wbv = *(const float4*)wbrow;
    float xv = xrow0[lane];
    float xn = xrow0[(size_t)BSZ * INDIM + lane];
    float b3prev = 0.f;
    __syncthreads();  // prologue

    {  // phase 0: beta_0
      float p0 = wave_sum64(wbv.x * xv);
      float p1 = wave_sum64(wbv.y * xv);
      float p2 = wave_sum64(wbv.z * xv);
      float p3 = wave_sum64(wbv.w * xv);
      float b0 = __fdividef(1.f, 1.f + __expf(-p0));
      float b1 = __fdividef(1.f, 1.f + __expf(-p1));
      float b2 = __fdividef(1.f, 1.f + __expf(-p2));
      float b3 = __fdividef(1.f, 1.f + __expf(-p3));
      if (lane == 0) *(float4*)(&betabuf[0][0]) = (float4){b0, b1, b2, b3};
      b3prev = b3;
      xv = xn;
      xn = xrow0[(size_t)2 * BSZ * INDIM + lane];
      __syncthreads();
    }
    for (int t = 1; t < SLEN; ++t) {
      const int bp = (t - 1) & 1;
      float4 ss4 = *(const float4*)(&ssub[bp][0]);
      float eq = eqk[bp][0][lane];
      float ek = eqk[bp][1][lane];
      float rq = __fdividef(1.f, ss4.x + ss4.y);
      float rk = __fdividef(1.f, ss4.z + ss4.w);
      float qv = rq * eq, kv = rk * ek;
      float qmk = qv - kv;
      float g0 = wave_sum64(wbv.x * qmk);
      float g1 = wave_sum64(wbv.y * qmk);
      float g2 = wave_sum64(wbv.z * qmk);
      float g3 = wave_sum64(wbv.w * qmk);
      float cl = b3prev * kv;
      wbv.x += cl * g0; wbv.y += cl * g1; wbv.z += cl * g2; wbv.w += cl * g3;
      // beta_t with updated wb and x_t
      float p0 = wave_sum64(wbv.x * xv);
      float p1 = wave_sum64(wbv.y * xv);
      float p2 = wave_sum64(wbv.z * xv);
      float p3 = wave_sum64(wbv.w * xv);
      float b0 = __fdividef(1.f, 1.f + __expf(-p0));
      float b1 = __fdividef(1.f, 1.f + __expf(-p1));
      float b2 = __fdividef(1.f, 1.f + __expf(-p2));
      float b3 = __fdividef(1.f, 1.f + __expf(-p3));
      if (lane == 0) *(float4*)(&betabuf[t & 1][0]) = (float4){b0, b1, b2, b3};
      b3prev = b3;
      xv = xn;
      if (t + 2 < SLEN) xn = xrow0[(size_t)(t + 2) * BSZ * INDIM + lane];
      __syncthreads();
    }
  } else {
    // wave 7: x staging, 3 steps ahead, triple-buffered
    xbuf[1][lane] = xrow0[(size_t)BSZ * INDIM + lane];          // x_1
    xbuf[2][lane] = xrow0[(size_t)2 * BSZ * INDIM + lane];      // x_2
    float g1 = xrow0[(size_t)3 * BSZ * INDIM + lane];           // x_3
    __syncthreads();  // prologue

    for (int t = 0; t < SLEN; ++t) {
      if (t + 3 < SLEN) xbuf[t % 3][lane] = g1;                 // x_{t+3}
      if (t + 4 < SLEN) g1 = xrow0[(size_t)(t + 4) * BSZ * INDIM + lane];
      __syncthreads();
    }
  }
#undef PHASE
#undef PUBLISH
}

// --------------------------------------------------------------------------
// GEMM accumulate: out += ys_bf16 @ out_w_bf16^T   (out pre-filled with h_ln)
// M=2048, N=1024, K=1024. 512 blocks: 64x64 tile, 4 waves of 32x32.
// Depth-3 chunk prefetch; XCD-chunked block swizzle.
// --------------------------------------------------------------------------
__global__ __launch_bounds__(256, 2) void gemm_acc_k(
    const unsigned short* __restrict__ A,
    const unsigned short* __restrict__ B,
    float* __restrict__ out) {
  const int bid0 = blockIdx.x;
  const int swz = (bid0 & 7) * 64 + (bid0 >> 3);  // XCD gets contiguous chunk
  const int bx = swz & 15;   // N tile (1024/64)
  const int by = swz >> 4;   // M tile (2048/64) -> 0..31
  const int tid = threadIdx.x;
  const int wave = tid >> 6, lane = tid & 63;
  const int wr = wave >> 1, wc = wave & 1;
  const int rbase = by * 64 + wr * 32;
  const int nbase = bx * 64 + wc * 32;
  const int l16 = lane & 15;
  const int kofs = (lane >> 4) * 8;

  const short* Ap = (const short*)A;
  const short* Bp = (const short*)B;

  f32x4 acc[2][2];
  #pragma unroll
  for (int i = 0; i < 2; ++i)
    #pragma unroll
    for (int j = 0; j < 2; ++j)
      acc[i][j] = (f32x4){0.f, 0.f, 0.f, 0.f};

  const short* arow[2];
  const short* brow[2];
  #pragma unroll
  for (int i = 0; i < 2; ++i)
    arow[i] = Ap + (size_t)(rbase + i * 16 + l16) * INDIM + kofs;
  #pragma unroll
  for (int j = 0; j < 2; ++j)
    brow[j] = Bp + (size_t)(nbase + j * 16 + l16) * INDIM + kofs;

  bf16x8 Ab[4][2], Bb[4][2];
  #pragma unroll
  for (int c = 0; c < 3; ++c)
    #pragma unroll
    for (int i = 0; i < 2; ++i) {
      Ab[c][i] = *(const bf16x8*)(arow[i] + c * 32);
      Bb[c][i] = *(const bf16x8*)(brow[i] + c * 32);
    }

  #pragma unroll
  for (int c = 0; c < 32; ++c) {
    if (c + 3 < 32) {
      const int pb = (c + 3) & 3;
      #pragma unroll
      for (int i = 0; i < 2; ++i) {
        Ab[pb][i] = *(const bf16x8*)(arow[i] + (c + 3) * 32);
        Bb[pb][i] = *(const bf16x8*)(brow[i] + (c + 3) * 32);
      }
    }
    #pragma unroll
    for (int i = 0; i < 2; ++i)
      #pragma unroll
      for (int j = 0; j < 2; ++j)
        acc[i][j] = __builtin_amdgcn_mfma_f32_16x16x32_bf16(Ab[c & 3][i], Bb[c & 3][j], acc[i][j], 0, 0, 0);
  }

  const int rq4 = (lane >> 4) * 4;
  #pragma unroll
  for (int i = 0; i < 2; ++i) {
    #pragma unroll
    for (int reg = 0; reg < 4; ++reg) {
      int r = rbase + i * 16 + rq4 + reg;
      #pragma unroll
      for (int j = 0; j < 2; ++j) {
        int n = nbase + j * 16 + l16;
        size_t idx = (size_t)r * INDIM + n;
        out[idx] += acc[i][j][reg];
      }
    }
  }
}

// --------------------------------------------------------------------------
extern "C" void kernel_launch(void* const* d_in, const int* in_sizes, int n_in,
                              void* d_out, int out_size, void* d_ws, size_t ws_size,
                              hipStream_t stream) {
  const float* h    = (const float*)d_in[0];
  const float* Wy   = (const float*)d_in[1];
  const float* Wq   = (const float*)d_in[2];
  const float* Wk   = (const float*)d_in[3];
  const float* wb   = (const float*)d_in[4];
  const float* outw = (const float*)d_in[5];
  const float* gam  = (const float*)d_in[6];
  const float* bet  = (const float*)d_in[7];
  float* out = (float*)d_out;

  char* ws = (char*)d_ws;
  unsigned short* ys_bf   = (unsigned short*)ws;                                  // 4 MB
  unsigned short* outw_bf = (unsigned short*)(ws + (size_t)2048 * 1024 * 2);      // 2 MB

  scan_prep_k<<<128 + 512 + 2048, 512, 0, stream>>>(h, Wy, Wq, Wk, wb, outw,
                                                    gam, bet, outw_bf, out, ys_bf);
  gemm_acc_k<<<512, 256, 0, stream>>>(ys_bf, outw_bf, out);
}